// Round 8
// baseline (280.852 us; speedup 1.0000x reference)
//
#include <hip/hip_runtime.h>
#include <cstdint>
#include <cstddef>

// ---------------------------------------------------------------------------
// Style2ResidualBlock1DSrc: modulated conv1d (StyleGAN2-style) on MI355X.
// bf16 MFMA GEMM pipeline. R7:
//  - gemm: B operand moved OFF the LDS pipe — loaded global->VGPR per frag
//    (L1-resident, tap re-reads hit L1). LDS carries only A, PRE-FRAGGED
//    (frag-major, lane-linear: ds_read_b128 stride-1 = m97 pattern, 0
//    conflicts, no swizzle math) and double-buffered so the single per-iter
//    barrier drains a stage issued one full compute phase earlier.
//    R3-R6 all measured per-iter = LDS + MFMA SUMMED (barrier convoy on both
//    operands); B-on-VMEM decouples via vmcnt scheduling, no barrier.
// ---------------------------------------------------------------------------

#define LIN_SCALE  0.0625f           // 1/sqrt(256)
#define CONV_SCALE 0.014731391f      // 1/sqrt(512*9)

#define B_   16
#define CIN  512
#define COUT 512
#define T_   2048
#define TP   2050                    // T + 2 pad rows

typedef __bf16 bf16x8 __attribute__((ext_vector_type(8)));
typedef float  f32x4  __attribute__((ext_vector_type(4)));
typedef unsigned short u16x8 __attribute__((ext_vector_type(8)));
typedef unsigned short u16x2 __attribute__((ext_vector_type(2)));

#define AS1 __attribute__((address_space(1)))
#define AS3 __attribute__((address_space(3)))

__device__ inline unsigned short f2bf(float f) {
  __bf16 h = (__bf16)f;              // RNE fptrunc
  return __builtin_bit_cast(unsigned short, h);
}

// ---------------- 1. style linear: s[b][i] ----------------
__global__ __launch_bounds__(256) void style_kernel(const float* __restrict__ c_src,
                                                    const float* __restrict__ c_trg,
                                                    const float* __restrict__ sw,
                                                    const float* __restrict__ sb,
                                                    float* __restrict__ s) {
  __shared__ float c[256];
  const int b = blockIdx.y;
  const int tid = threadIdx.x;
  c[tid] = (tid < 128) ? c_src[b * 128 + tid] : c_trg[b * 128 + tid - 128];
  __syncthreads();
  const int w = tid >> 6, lane = tid & 63;
  #pragma unroll
  for (int rr = 0; rr < 16; ++rr) {
    const int i = blockIdx.x * 64 + w * 16 + rr;
    const float* row = sw + (size_t)i * 256;
    float acc = row[lane] * c[lane] + row[lane + 64] * c[lane + 64]
              + row[lane + 128] * c[lane + 128] + row[lane + 192] * c[lane + 192];
    #pragma unroll
    for (int off = 32; off; off >>= 1) acc += __shfl_down(acc, off, 64);
    if (lane == 0) s[b * 512 + i] = acc * LIN_SCALE + sb[i];
  }
}

// ---------------- 2. modulate + demodulate -> bf16 W[b][tap][o][i] ----------------
__global__ __launch_bounds__(256) void modw_kernel(const float* __restrict__ weight,
                                                   const float* __restrict__ s,
                                                   unsigned short* __restrict__ Wm) {
  const int o = blockIdx.x;
  const int tid = threadIdx.x;
  __shared__ float wsh[1536];        // weight[o][:][:]
  __shared__ float svs[16 * 512];    // all style vectors (32 KB)
  __shared__ float partial[16][4];
  __shared__ float demv[16];

  #pragma unroll
  for (int j = tid; j < 1536; j += 256) wsh[j] = weight[(size_t)o * 1536 + j];
  #pragma unroll
  for (int j = tid; j < 16 * 512; j += 256) svs[j] = s[j];
  __syncthreads();

  float wr[6];
  #pragma unroll
  for (int q = 0; q < 6; ++q) wr[q] = wsh[tid * 6 + q] * CONV_SCALE;

  const int lane = tid & 63, w = tid >> 6;
  float ssb[16];
  #pragma unroll
  for (int b = 0; b < 16; ++b) {
    const float s0 = svs[b * 512 + 2 * tid];
    const float s1 = svs[b * 512 + 2 * tid + 1];
    float ss = 0.f;
    #pragma unroll
    for (int q = 0; q < 3; ++q) { float v = wr[q] * s0; ss += v * v; }
    #pragma unroll
    for (int q = 3; q < 6; ++q) { float v = wr[q] * s1; ss += v * v; }
    ssb[b] = ss;
  }
  #pragma unroll
  for (int b = 0; b < 16; ++b) {
    float ss = ssb[b];
    #pragma unroll
    for (int off = 32; off; off >>= 1) ss += __shfl_down(ss, off, 64);
    if (lane == 0) partial[b][w] = ss;
  }
  __syncthreads();
  if (tid < 16)
    demv[tid] = rsqrtf(partial[tid][0] + partial[tid][1] + partial[tid][2] + partial[tid][3] + 1e-8f);
  __syncthreads();

  #pragma unroll
  for (int b = 0; b < 16; ++b) {
    const float dem = demv[b];
    const float s0 = svs[b * 512 + 2 * tid] * dem;
    const float s1 = svs[b * 512 + 2 * tid + 1] * dem;
    #pragma unroll
    for (int k = 0; k < 3; ++k) {
      u16x2 v;
      v.x = f2bf(wr[k] * s0);
      v.y = f2bf(wr[3 + k] * s1);
      *(u16x2*)&Wm[(((size_t)b * 3 + k) * 512 + o) * 512 + 2 * tid] = v;
    }
  }
}

// ---------------- 3. transpose + pad + bf16 (+ fused zpad) ----------------
__global__ __launch_bounds__(256) void transpose_kernel(const float* __restrict__ x,
                                                        unsigned short* __restrict__ xT) {
  __shared__ float tile[64][65];
  const int b = blockIdx.z, i0 = blockIdx.y * 64, t0 = blockIdx.x * 64;
  const int tid = threadIdx.x;

  const int lr = tid >> 4;            // 0..15
  const int lc = (tid & 15) * 4;      // float4
  const float* xb = x + ((size_t)b * CIN + i0) * T_ + t0;
  #pragma unroll
  for (int p = 0; p < 4; ++p) {
    const int r = p * 16 + lr;
    const float4 v = *(const float4*)(xb + (size_t)r * T_ + lc);
    tile[r][lc + 0] = v.x; tile[r][lc + 1] = v.y;
    tile[r][lc + 2] = v.z; tile[r][lc + 3] = v.w;
  }
  // fused zero-pad of rows 0 and 2049 (no barrier dependency)
  if (blockIdx.x == 0 && tid < 8)
    *(u16x8*)&xT[(size_t)b * TP * CIN + i0 + tid * 8] = (u16x8){0,0,0,0,0,0,0,0};
  if (blockIdx.x == gridDim.x - 1 && tid < 8)
    *(u16x8*)&xT[((size_t)b * TP + TP - 1) * CIN + i0 + tid * 8] = (u16x8){0,0,0,0,0,0,0,0};
  __syncthreads();

  const int st = tid >> 3;            // 0..31
  const int si = (tid & 7) * 8;       // 16B
  unsigned short* xTb = xT + ((size_t)b * TP + 1 + t0) * CIN + i0;
  #pragma unroll
  for (int p = 0; p < 2; ++p) {
    const int t = p * 32 + st;
    u16x8 v;
    #pragma unroll
    for (int q = 0; q < 8; ++q) v[q] = f2bf(tile[si + q][t]);
    *(u16x8*)&xTb[(size_t)t * CIN + si] = v;
  }
}

// ---------------- 4. main GEMM: A pre-fragged LDS (dbuf), B global->VGPR ----------------
// out[b][o0..+128][t0..+128] = sum_{tap,i} Wm[b][tap][o][i] * xT[b][t0+n+tap][i]
// A frag f = tap*8 + g (g = o-row/16): lA[buf][f*64 + lane]*16B, lane-linear
// (frag layout A[m=lane&15][k=(lane>>4)*8+j]). ds_read stride-1, 0 conflicts.
// B frags: direct global bf16x8 loads (L1-resident tile), no barrier coupling.
// 4 waves 2x2, wave 64x64 via 4x4 16x16x32 frags. Grid 1024.
#define BM 128
#define BN 128
#define AFRAGS 24                    // 3 taps x 8 m-groups
#define ABUF (AFRAGS * 64 * 8)       // shorts per buffer (24 KB)

__global__ __launch_bounds__(256, 2) void gemm_kernel(const unsigned short* __restrict__ Wm,
                                                      const unsigned short* __restrict__ xT,
                                                      float* __restrict__ out) {
  __shared__ unsigned short lA[2 * ABUF];   // 49152 B

  // XCD b-grouping: 1024 blocks; ids == xcd (mod 8); 2 batches per XCD.
  const int id  = blockIdx.x;
  const int xcd = id & 7;
  const int j   = id >> 3;                 // 0..127
  const int b   = xcd + 8 * (j >> 6);      // 0..15
  const int r   = j & 63;
  const int o0  = (r >> 4) * BM;           // 4 o-blocks
  const int t0  = (r & 15) * BN;           // 16 t-blocks

  const int tid  = threadIdx.x;
  const int lane = tid & 63;
  const int wid  = tid >> 6;
  const int wm   = (wid & 1) * 64;         // wave M offset
  const int wn   = (wid >> 1) * 64;        // wave N offset
  const int ga   = (wid & 1) * 4;          // wave's A m-group base

  const unsigned short* gW = Wm + ((size_t)b * 3 * 512 + o0) * 512;
  // B lane base: row = t0+wn+(lane&15) (+ni*16+tap), col = (lane>>4)*8 (+i0)
  const unsigned short* gX = xT + ((size_t)b * TP + t0 + wn + (lane & 15)) * 512
                                + ((lane >> 4) * 8);

  // A staging descriptors: 1536 chunks, 6 per thread; chunk ci -> frag f=ci>>6,
  // frag-lane l=ci&63; src row = g*16+(l&15), src col = (l>>4)*8.
  int sSrc[6], sDst[6];
  #pragma unroll
  for (int q = 0; q < 6; ++q) {
    const int ci = q * 256 + tid;
    const int f  = ci >> 6;
    const int l  = ci & 63;
    const int tap = f >> 3, g = f & 7;
    sSrc[q] = tap * 262144 + (g * 16 + (l & 15)) * 512 + ((l >> 4) * 8);
    sDst[q] = ci * 8;
  }

  f32x4 acc[4][4];
  #pragma unroll
  for (int i = 0; i < 4; ++i)
    #pragma unroll
    for (int jj = 0; jj < 4; ++jj) acc[i][jj] = (f32x4){0.f, 0.f, 0.f, 0.f};

  // Prologue: stage A buffer 0 (i0 = 0).
  #pragma unroll
  for (int q = 0; q < 6; ++q)
    __builtin_amdgcn_global_load_lds((const AS1 void*)(gW + sSrc[q]),
                                     (AS3 void*)(&lA[sDst[q]]), 16, 0, 0);

  for (int kk = 0; kk < 16; ++kk) {
    const int i0  = kk * 32;
    const int cur = (kk & 1) * ABUF;
    const int nxt = ((kk & 1) ^ 1) * ABUF;

    // Single barrier: drains A[cur] stage (issued a full iter ago — free);
    // signals A[nxt] buffer free for restage.
    __syncthreads();

    // Stage A[nxt] now — overlaps all compute below.
    if (kk < 15) {
      const int i0n = i0 + 32;
      #pragma unroll
      for (int q = 0; q < 6; ++q)
        __builtin_amdgcn_global_load_lds((const AS1 void*)(gW + sSrc[q] + i0n),
                                         (AS3 void*)(&lA[nxt + sDst[q]]), 16, 0, 0);
    }

    // B frags for all taps: VMEM pipe, vmcnt-scheduled against MFMA.
    bf16x8 bfr[3][4];
    #pragma unroll
    for (int tap = 0; tap < 3; ++tap)
      #pragma unroll
      for (int ni = 0; ni < 4; ++ni)
        bfr[tap][ni] = *(const bf16x8*)(gX + (size_t)(ni * 16 + tap) * 512 + i0);

    #pragma unroll
    for (int tap = 0; tap < 3; ++tap) {
      bf16x8 af[4];
      #pragma unroll
      for (int mi = 0; mi < 4; ++mi)
        af[mi] = *(const bf16x8*)&lA[cur + ((tap * 8 + ga + mi) * 64 + lane) * 8];
      #pragma unroll
      for (int mi = 0; mi < 4; ++mi)
        #pragma unroll
        for (int ni = 0; ni < 4; ++ni)
          acc[mi][ni] = __builtin_amdgcn_mfma_f32_16x16x32_bf16(af[mi], bfr[tap][ni], acc[mi][ni], 0, 0, 0);
    }
  }

  // epilogue: D row = (lane>>4)*4 + reg, col = lane&15 (m89 mapping)
  float* ob = out + ((size_t)b * COUT + o0 + wm) * T_ + t0 + wn;
  const int rrow = (lane >> 4) * 4;
  const int ccol = lane & 15;
  #pragma unroll
  for (int mi = 0; mi < 4; ++mi)
    #pragma unroll
    for (int ni = 0; ni < 4; ++ni)
      #pragma unroll
      for (int rr = 0; rr < 4; ++rr)
        ob[(size_t)(mi * 16 + rrow + rr) * T_ + ni * 16 + ccol] = acc[mi][ni][rr];
}

// ---------------------------------------------------------------------------
extern "C" void kernel_launch(void* const* d_in, const int* in_sizes, int n_in,
                              void* d_out, int out_size, void* d_ws, size_t ws_size,
                              hipStream_t stream) {
  const float* x       = (const float*)d_in[0];   // [16,512,2048]
  const float* c_src   = (const float*)d_in[1];   // [16,128]
  const float* c_trg   = (const float*)d_in[2];   // [16,128]
  const float* style_w = (const float*)d_in[3];   // [512,256]
  const float* style_b = (const float*)d_in[4];   // [512]
  const float* weight  = (const float*)d_in[5];   // [1,512,512,3]
  float* out = (float*)d_out;

  // workspace: s_buf fp32 [16][512] @0; Wm bf16 [16][3][512][512] @32768;
  //            xT bf16 [16][2050][512] @25198592
  char* ws = (char*)d_ws;
  float* s_buf          = (float*)ws;
  unsigned short* Wm    = (unsigned short*)(ws + 32768);
  unsigned short* xTbuf = (unsigned short*)(ws + 32768 + 25165824);

  style_kernel<<<dim3(8, 16), 256, 0, stream>>>(c_src, c_trg, style_w, style_b, s_buf);
  modw_kernel<<<dim3(COUT), 256, 0, stream>>>(weight, s_buf, Wm);
  transpose_kernel<<<dim3(T_ / 64, CIN / 64, B_), 256, 0, stream>>>(x, xTbuf);
  gemm_kernel<<<dim3(1024), 256, 0, stream>>>(Wm, xTbuf, out);
}

// Round 9
// 190.198 us; speedup vs baseline: 1.4766x; 1.4766x over previous
//
#include <hip/hip_runtime.h>
#include <cstdint>
#include <cstddef>

// ---------------------------------------------------------------------------
// Style2ResidualBlock1DSrc: modulated conv1d (StyleGAN2-style) on MI355X.
// bf16 MFMA GEMM pipeline. R8: producer-consumer wave specialization.
// R3-R7 all measured per-iter = LDS-pipe + MFMA-pipe SUMMED (the barrier's
// implicit vmcnt(0)/lgkmcnt(0) convoy). Here: 4 consumer waves (64x128 tiles,
// R3's exact frag/swizzle math) never issue a vmem op in the K-loop; 1
// producer wave does all global->LDS staging into double-buffered lA/lB;
// sync via LDS atomics (ready/done counters), ONE __syncthreads total.
// ---------------------------------------------------------------------------

#define LIN_SCALE  0.0625f           // 1/sqrt(256)
#define CONV_SCALE 0.014731391f      // 1/sqrt(512*9)

#define B_   16
#define CIN  512
#define COUT 512
#define T_   2048
#define TP   2050                    // T + 2 pad rows

typedef __bf16 bf16x8 __attribute__((ext_vector_type(8)));
typedef float  f32x4  __attribute__((ext_vector_type(4)));
typedef unsigned short u16x8 __attribute__((ext_vector_type(8)));
typedef unsigned short u16x2 __attribute__((ext_vector_type(2)));

#define AS1 __attribute__((address_space(1)))
#define AS3 __attribute__((address_space(3)))

__device__ inline unsigned short f2bf(float f) {
  __bf16 h = (__bf16)f;              // RNE fptrunc
  return __builtin_bit_cast(unsigned short, h);
}

// ---------------- 1. style linear: s[b][i] ----------------
__global__ __launch_bounds__(256) void style_kernel(const float* __restrict__ c_src,
                                                    const float* __restrict__ c_trg,
                                                    const float* __restrict__ sw,
                                                    const float* __restrict__ sb,
                                                    float* __restrict__ s) {
  __shared__ float c[256];
  const int b = blockIdx.y;
  const int tid = threadIdx.x;
  c[tid] = (tid < 128) ? c_src[b * 128 + tid] : c_trg[b * 128 + tid - 128];
  __syncthreads();
  const int w = tid >> 6, lane = tid & 63;
  #pragma unroll
  for (int rr = 0; rr < 16; ++rr) {
    const int i = blockIdx.x * 64 + w * 16 + rr;
    const float* row = sw + (size_t)i * 256;
    float acc = row[lane] * c[lane] + row[lane + 64] * c[lane + 64]
              + row[lane + 128] * c[lane + 128] + row[lane + 192] * c[lane + 192];
    #pragma unroll
    for (int off = 32; off; off >>= 1) acc += __shfl_down(acc, off, 64);
    if (lane == 0) s[b * 512 + i] = acc * LIN_SCALE + sb[i];
  }
}

// ---------------- 2. modulate + demodulate -> bf16 W[b][tap][o][i] ----------------
__global__ __launch_bounds__(256) void modw_kernel(const float* __restrict__ weight,
                                                   const float* __restrict__ s,
                                                   unsigned short* __restrict__ Wm) {
  const int o = blockIdx.x;
  const int tid = threadIdx.x;
  __shared__ float wsh[1536];        // weight[o][:][:]
  __shared__ float svs[16 * 512];    // all style vectors (32 KB)
  __shared__ float partial[16][4];
  __shared__ float demv[16];

  #pragma unroll
  for (int j = tid; j < 1536; j += 256) wsh[j] = weight[(size_t)o * 1536 + j];
  #pragma unroll
  for (int j = tid; j < 16 * 512; j += 256) svs[j] = s[j];
  __syncthreads();

  float wr[6];
  #pragma unroll
  for (int q = 0; q < 6; ++q) wr[q] = wsh[tid * 6 + q] * CONV_SCALE;

  const int lane = tid & 63, w = tid >> 6;
  float ssb[16];
  #pragma unroll
  for (int b = 0; b < 16; ++b) {
    const float s0 = svs[b * 512 + 2 * tid];
    const float s1 = svs[b * 512 + 2 * tid + 1];
    float ss = 0.f;
    #pragma unroll
    for (int q = 0; q < 3; ++q) { float v = wr[q] * s0; ss += v * v; }
    #pragma unroll
    for (int q = 3; q < 6; ++q) { float v = wr[q] * s1; ss += v * v; }
    ssb[b] = ss;
  }
  #pragma unroll
  for (int b = 0; b < 16; ++b) {
    float ss = ssb[b];
    #pragma unroll
    for (int off = 32; off; off >>= 1) ss += __shfl_down(ss, off, 64);
    if (lane == 0) partial[b][w] = ss;
  }
  __syncthreads();
  if (tid < 16)
    demv[tid] = rsqrtf(partial[tid][0] + partial[tid][1] + partial[tid][2] + partial[tid][3] + 1e-8f);
  __syncthreads();

  #pragma unroll
  for (int b = 0; b < 16; ++b) {
    const float dem = demv[b];
    const float s0 = svs[b * 512 + 2 * tid] * dem;
    const float s1 = svs[b * 512 + 2 * tid + 1] * dem;
    #pragma unroll
    for (int k = 0; k < 3; ++k) {
      u16x2 v;
      v.x = f2bf(wr[k] * s0);
      v.y = f2bf(wr[3 + k] * s1);
      *(u16x2*)&Wm[(((size_t)b * 3 + k) * 512 + o) * 512 + 2 * tid] = v;
    }
  }
}

// ---------------- 3. transpose + pad + bf16 (+ fused zpad) ----------------
__global__ __launch_bounds__(256) void transpose_kernel(const float* __restrict__ x,
                                                        unsigned short* __restrict__ xT) {
  __shared__ float tile[64][65];
  const int b = blockIdx.z, i0 = blockIdx.y * 64, t0 = blockIdx.x * 64;
  const int tid = threadIdx.x;

  const int lr = tid >> 4;            // 0..15
  const int lc = (tid & 15) * 4;      // float4
  const float* xb = x + ((size_t)b * CIN + i0) * T_ + t0;
  #pragma unroll
  for (int p = 0; p < 4; ++p) {
    const int r = p * 16 + lr;
    const float4 v = *(const float4*)(xb + (size_t)r * T_ + lc);
    tile[r][lc + 0] = v.x; tile[r][lc + 1] = v.y;
    tile[r][lc + 2] = v.z; tile[r][lc + 3] = v.w;
  }
  // fused zero-pad of rows 0 and 2049 (no barrier dependency)
  if (blockIdx.x == 0 && tid < 8)
    *(u16x8*)&xT[(size_t)b * TP * CIN + i0 + tid * 8] = (u16x8){0,0,0,0,0,0,0,0};
  if (blockIdx.x == gridDim.x - 1 && tid < 8)
    *(u16x8*)&xT[((size_t)b * TP + TP - 1) * CIN + i0 + tid * 8] = (u16x8){0,0,0,0,0,0,0,0};
  __syncthreads();

  const int st = tid >> 3;            // 0..31
  const int si = (tid & 7) * 8;       // 16B
  unsigned short* xTb = xT + ((size_t)b * TP + 1 + t0) * CIN + i0;
  #pragma unroll
  for (int p = 0; p < 2; ++p) {
    const int t = p * 32 + st;
    u16x8 v;
    #pragma unroll
    for (int q = 0; q < 8; ++q) v[q] = f2bf(tile[si + q][t]);
    *(u16x8*)&xTb[(size_t)t * CIN + si] = v;
  }
}

// ---------------- 4. main GEMM: producer-consumer waves ----------------
// out[b][o0..+128][t0..+256] = sum_{tap,i} Wm[b][tap][o][i] * xT[b][t0+n+tap][i]
// 320 threads: waves 0-3 = consumers (2x2 grid, each 64x128 via 4x8 16x16x32
// frags, R3's exact swizzle c^((row>>1)&3)); wave 4 = producer (all staging).
// lA[2][3*128*32] + lB[2][258*32] = 82.2 KB -> 1 block/CU. Sync: LDS atomics.
#define BM 128
#define BN 256
#define BK 32
#define LA_SZ (3 * 128 * 32)         // shorts per lA buffer
#define LB_SZ (258 * 32)             // shorts per lB buffer

__global__ __launch_bounds__(320, 1) void gemm_kernel(const unsigned short* __restrict__ Wm,
                                                      const unsigned short* __restrict__ xT,
                                                      float* __restrict__ out) {
  __shared__ unsigned short lA[2 * LA_SZ];   // 49152 B
  __shared__ unsigned short lB[2 * LB_SZ];   // 33024 B
  __shared__ int ready[2];                   // stagings completed per buffer
  __shared__ int done[2];                    // consumer-wave completions per buffer

  // XCD b-grouping: 512 blocks; ids == xcd (mod 8); 2 batches per XCD.
  const int id  = blockIdx.x;
  const int xcd = id & 7;
  const int j   = id >> 3;                 // 0..63
  const int b   = xcd + 8 * (j >> 5);      // 0..15
  const int r   = j & 31;
  const int o0  = (r >> 3) * BM;           // 4 o-blocks
  const int t0  = (r & 7) * BN;            // 8 t-blocks

  const int tid  = threadIdx.x;
  const int lane = tid & 63;
  const int wid  = tid >> 6;               // 0..4

  const unsigned short* gW = Wm + ((size_t)b * 3 * 512 + o0) * 512;
  const unsigned short* gX = xT + ((size_t)b * TP + t0) * CIN;

  if (tid < 2) { ready[tid] = 0; done[tid] = 0; }
  __syncthreads();                         // the ONLY barrier

  if (wid == 4) {
    // ---------------- producer wave ----------------
    for (int kk = 0; kk < 16; ++kk) {
      const int p  = kk & 1;
      const int u  = kk >> 1;
      const int i0 = kk * 32;
      // wait until consumers finished previous use of buffer p
      while (__hip_atomic_load(&done[p], __ATOMIC_ACQUIRE, __HIP_MEMORY_SCOPE_WORKGROUP) < 4 * u)
        __builtin_amdgcn_s_sleep(1);
      // A: 1536 chunks, 24 instr; chunk ci -> row=ci>>2 (tap*128+ar), col swizzled
      #pragma unroll
      for (int q = 0; q < 24; ++q) {
        const int ci  = q * 64 + lane;
        const int row = ci >> 2;
        const int tap = row >> 7;
        const int ar  = row & 127;
        const int gc  = ((ci & 3) ^ ((ar >> 1) & 3)) * 8;
        __builtin_amdgcn_global_load_lds(
            (const AS1 void*)(gW + (size_t)tap * 262144 + (size_t)ar * 512 + i0 + gc),
            (AS3 void*)(&lA[p * LA_SZ + ci * 8]), 16, 0, 0);
      }
      // B: 1032 chunks (258 rows x 4), 17 instr (last partial)
      #pragma unroll
      for (int q = 0; q < 17; ++q) {
        const int ci = q * 64 + lane;
        if (ci < 1032) {
          const int row = ci >> 2;
          const int gc  = ((ci & 3) ^ ((row >> 1) & 3)) * 8;
          __builtin_amdgcn_global_load_lds(
              (const AS1 void*)(gX + (size_t)row * CIN + i0 + gc),
              (AS3 void*)(&lB[p * LB_SZ + ci * 8]), 16, 0, 0);
        }
      }
      __threadfence_block();               // drain vmcnt: LDS writes visible
      if (lane == 0)
        __hip_atomic_fetch_add(&ready[p], 1, __ATOMIC_RELEASE, __HIP_MEMORY_SCOPE_WORKGROUP);
    }
    return;
  }

  // ---------------- consumer waves (R3 compute verbatim) ----------------
  const int wm = (wid & 1) * 64;           // wave M offset
  const int wn = (wid >> 1) * 128;         // wave N offset
  const int rl = lane & 15;
  const int kc = lane >> 4;                // chunk 0..3 within 32-wide row

  f32x4 acc[4][8];
  #pragma unroll
  for (int i = 0; i < 4; ++i)
    #pragma unroll
    for (int jj = 0; jj < 8; ++jj) acc[i][jj] = (f32x4){0.f, 0.f, 0.f, 0.f};

  for (int kk = 0; kk < 16; ++kk) {
    const int p = kk & 1;
    const int u = kk >> 1;
    // wait for staging u of buffer p (acquire: frag reads can't hoist above)
    while (__hip_atomic_load(&ready[p], __ATOMIC_ACQUIRE, __HIP_MEMORY_SCOPE_WORKGROUP) < u + 1)
      __builtin_amdgcn_s_sleep(1);
    const int ca = p * LA_SZ;
    const int cb = p * LB_SZ;

    #pragma unroll
    for (int tap = 0; tap < 3; ++tap) {
      bf16x8 af[4], bfr[8];
      #pragma unroll
      for (int mi = 0; mi < 4; ++mi) {
        const int ra = wm + mi * 16 + rl;
        af[mi] = *(const bf16x8*)&lA[ca + ((tap * 128 + ra) * 4 + (kc ^ ((ra >> 1) & 3))) * 8];
      }
      #pragma unroll
      for (int ni = 0; ni < 8; ++ni) {
        const int rb = wn + ni * 16 + rl + tap;
        bfr[ni] = *(const bf16x8*)&lB[cb + (rb * 4 + (kc ^ ((rb >> 1) & 3))) * 8];
      }
      #pragma unroll
      for (int mi = 0; mi < 4; ++mi)
        #pragma unroll
        for (int ni = 0; ni < 8; ++ni)
          acc[mi][ni] = __builtin_amdgcn_mfma_f32_16x16x32_bf16(af[mi], bfr[ni], acc[mi][ni], 0, 0, 0);
    }
    // release: forces prior ds_reads drained before signaling buffer free
    if (lane == 0)
      __hip_atomic_fetch_add(&done[p], 1, __ATOMIC_RELEASE, __HIP_MEMORY_SCOPE_WORKGROUP);
  }

  // epilogue: D row = (lane>>4)*4 + reg, col = lane&15 (m89 mapping)
  float* ob = out + ((size_t)b * COUT + o0 + wm) * T_ + t0 + wn;
  const int rrow = (lane >> 4) * 4;
  const int ccol = lane & 15;
  #pragma unroll
  for (int mi = 0; mi < 4; ++mi)
    #pragma unroll
    for (int ni = 0; ni < 8; ++ni)
      #pragma unroll
      for (int rr = 0; rr < 4; ++rr)
        ob[(size_t)(mi * 16 + rrow + rr) * T_ + ni * 16 + ccol] = acc[mi][ni][rr];
}

// ---------------------------------------------------------------------------
extern "C" void kernel_launch(void* const* d_in, const int* in_sizes, int n_in,
                              void* d_out, int out_size, void* d_ws, size_t ws_size,
                              hipStream_t stream) {
  const float* x       = (const float*)d_in[0];   // [16,512,2048]
  const float* c_src   = (const float*)d_in[1];   // [16,128]
  const float* c_trg   = (const float*)d_in[2];   // [16,128]
  const float* style_w = (const float*)d_in[3];   // [512,256]
  const float* style_b = (const float*)d_in[4];   // [512]
  const float* weight  = (const float*)d_in[5];   // [1,512,512,3]
  float* out = (float*)d_out;

  // workspace: s_buf fp32 [16][512] @0; Wm bf16 [16][3][512][512] @32768;
  //            xT bf16 [16][2050][512] @25198592
  char* ws = (char*)d_ws;
  float* s_buf          = (float*)ws;
  unsigned short* Wm    = (unsigned short*)(ws + 32768);
  unsigned short* xTbuf = (unsigned short*)(ws + 32768 + 25165824);

  style_kernel<<<dim3(8, 16), 256, 0, stream>>>(c_src, c_trg, style_w, style_b, s_buf);
  modw_kernel<<<dim3(COUT), 256, 0, stream>>>(weight, s_buf, Wm);
  transpose_kernel<<<dim3(T_ / 64, CIN / 64, B_), 256, 0, stream>>>(x, xTbuf);
  gemm_kernel<<<dim3(512), 320, 0, stream>>>(Wm, xTbuf, out);
}